// Round 6
// baseline (406.349 us; speedup 1.0000x reference)
//
#include <hip/hip_runtime.h>
#include <hip/hip_bf16.h>

typedef __bf16 bf16x8 __attribute__((ext_vector_type(8)));
typedef float f32x4 __attribute__((ext_vector_type(4)));

__device__ __forceinline__ unsigned short f2bf(float f) {
  union { float f; unsigned u; } x; x.f = f;
  unsigned r = x.u + 0x7fffu + ((x.u >> 16) & 1u);
  return (unsigned short)(r >> 16);
}
__device__ __forceinline__ float bf2f(unsigned short u) {
  union { unsigned u; float f; } x; x.u = (unsigned)u << 16;
  return x.f;
}
__device__ __forceinline__ unsigned short f2h(float f) {
  union { _Float16 h; unsigned short u; } x; x.h = (_Float16)f;
  return x.u;
}
__device__ __forceinline__ float h2f(unsigned short u) {
  union { _Float16 h; unsigned short u; } x; x.u = u;
  return (float)x.h;
}

__device__ __forceinline__ void async_ld16(const void* g, void* l) {
  __builtin_amdgcn_global_load_lds(
      (__attribute__((address_space(1))) void*)const_cast<void*>(g),
      (__attribute__((address_space(3))) void*)l, 16, 0, 0);
}

// ---------------- 128x256 double-buffered GEMM, 16 waves ----------------
// BM=128 x BN=256, BK=64, 1024 threads (16 waves: 4M x 4N), per-wave 32x64.
// Rationale vs round-5 256² 8-wave: acc shrinks 128->32 f32/wave so total
// regs/wave ~<=128 -> 4 waves/SIMD (vs 2): stage/vmcnt/barrier windows of one
// wave hide under other waves' MFMAs (round-5 counters: MFMA 28% / VALU 17% /
// HBM 13% => wait-bound at 2 waves/SIMD).
// LDS: 2 buffers x (A 128x64 + B 256x64) bf16 = 96 KB.
// Schedule (per K-tile, verified ledger from r5): barA (all waves done
// reading t-1); STAGE tile t+1 into buf[(t+1)&1] (3 gload_lds/thread);
// s_waitcnt vmcnt(3) retires tile t's 3 loads (issued last iter; 3 of t+1
// stay in flight); barB (tile t published); ds_read+MFMA tile t.
// XOR swizzle (r4/r5-verified, 0 bank conflicts): LDS holds row r's k-group
// g at source k-group g^(r&7); ds_read applies same XOR.

#define EPI_F32    0
#define EPI_BF     1
#define EPI_RELUBF 2
#define EPI_F16    3

__global__ __launch_bounds__(1024, 4) void gemm_bt(
    const unsigned short* __restrict__ A,   // [nb][M][K] bf16
    const unsigned short* __restrict__ Bt,  // [nb][N][K] bf16
    int M, int N, int K, int nbatch,
    long sA, long sB, long sC,
    float scale, int mode, void* __restrict__ outp)
{
  __shared__ unsigned short lds[49152];  // 2 x (8192 A + 16384 B) elems = 96 KB
  const int t = threadIdx.x;
  const int w = t >> 6, l = t & 63;
  const int lr = l & 15, lg = l >> 4;
  const int wr = w >> 2, wc = w & 3;           // 4 M-waves x 4 N-waves
  const int ntn = N >> 8;                      // N/256
  const int tiles = (M >> 7) * ntn;            // per batch
  const int chunk = (tiles * nbatch) >> 3;
  const int bid = blockIdx.x;
  const int wg = (bid & 7) * chunk + (bid >> 3);
  const int batch = wg / tiles;
  const int rem = wg - batch * tiles;
  const int row0 = (rem / ntn) << 7;
  const int col0 = (rem % ntn) << 8;

  const unsigned short* Ab  = A  + (long)batch * sA;
  const unsigned short* Btb = Bt + (long)batch * sB;

  // staging: thread covers row rsub (A: rows 0..127; B: rows rsub, rsub+128)
  const int rsub = t >> 3;                       // 0..127
  const int cg8  = ((t & 7) ^ (rsub & 7)) << 3;  // swizzled k-offset (elems)
  const long arow  = (long)(row0 + rsub) * K;
  const long brow  = (long)(col0 + rsub) * K;
  const long bstep = (long)K << 7;               // 128 rows

  const int NT = K >> 6;

#define STAGE(buf, kk0)                                                     \
  {                                                                         \
    const unsigned short* sa = Ab + arow + (kk0) + cg8;                     \
    const unsigned short* sb = Btb + brow + (kk0) + cg8;                    \
    async_ld16(sa,         (buf) + t * 8);                                  \
    async_ld16(sb,         (buf) + 8192 + t * 8);                           \
    async_ld16(sb + bstep, (buf) + 16384 + t * 8);                          \
  }

  f32x4 acc[2][4];
#pragma unroll
  for (int m = 0; m < 2; ++m)
#pragma unroll
    for (int n = 0; n < 4; ++n) acc[m][n] = (f32x4){0.f, 0.f, 0.f, 0.f};

  // prologue: stage tile 0 into buf0
  STAGE(lds, 0);
  __builtin_amdgcn_sched_barrier(0);

  for (int tt = 0; tt < NT; ++tt) {
    unsigned short* ldsA = lds + (tt & 1) * 24576;
    unsigned short* ldsB = ldsA + 8192;
    unsigned short* ldsN = lds + ((tt + 1) & 1) * 24576;

    __builtin_amdgcn_s_barrier();              // A: all waves done reading t-1
    __builtin_amdgcn_sched_barrier(0);
    if (tt + 1 < NT) {
      STAGE(ldsN, (tt + 1) << 6);
      __builtin_amdgcn_sched_barrier(0);
      asm volatile("s_waitcnt vmcnt(3)" ::: "memory");   // retire tile t
    } else {
      asm volatile("s_waitcnt vmcnt(0)" ::: "memory");
    }
    __builtin_amdgcn_sched_barrier(0);
    __builtin_amdgcn_s_barrier();              // B: tile t published
    __builtin_amdgcn_sched_barrier(0);

#pragma unroll
    for (int kk = 0; kk < 2; ++kk) {
      bf16x8 af[2], bfr[4];
#pragma unroll
      for (int mf = 0; mf < 2; ++mf) {
        int Ra = wr * 32 + mf * 16 + lr;
        af[mf] = *(const bf16x8*)&ldsA[Ra * 64 + ((kk * 32 + lg * 8) ^ ((Ra & 7) << 3))];
      }
#pragma unroll
      for (int nf = 0; nf < 4; ++nf) {
        int Rb = wc * 64 + nf * 16 + lr;
        bfr[nf] = *(const bf16x8*)&ldsB[Rb * 64 + ((kk * 32 + lg * 8) ^ ((Rb & 7) << 3))];
      }
      __builtin_amdgcn_s_setprio(1);
#pragma unroll
      for (int mf = 0; mf < 2; ++mf)
#pragma unroll
        for (int nf = 0; nf < 4; ++nf)
          acc[mf][nf] = __builtin_amdgcn_mfma_f32_16x16x32_bf16(af[mf], bfr[nf], acc[mf][nf], 0, 0, 0);
      __builtin_amdgcn_s_setprio(0);
    }
    __builtin_amdgcn_sched_barrier(0);
  }

  float* outF = (float*)outp;
  unsigned short* outH = (unsigned short*)outp;
  const size_t cb = (size_t)batch * (size_t)sC;
#pragma unroll
  for (int mf = 0; mf < 2; ++mf) {
    int rbase = row0 + wr * 32 + mf * 16 + lg * 4;
#pragma unroll
    for (int nf = 0; nf < 4; ++nf) {
      int c = col0 + wc * 64 + nf * 16 + lr;
      f32x4 v = acc[mf][nf];
#pragma unroll
      for (int q = 0; q < 4; ++q) {
        size_t idx = cb + (size_t)(rbase + q) * N + c;
        float val = v[q] * scale;
        if (mode == EPI_F32)         outF[idx] = val;
        else if (mode == EPI_BF)     outH[idx] = f2bf(val);
        else if (mode == EPI_RELUBF) outH[idx] = f2bf(fmaxf(val, 0.f));
        else                         outH[idx] = f2h(val);
      }
    }
  }
#undef STAGE
}

// ---------------- elementwise / reduction kernels (unchanged) ----------------

__device__ __forceinline__ float wave_sum(float v) {
#pragma unroll
  for (int o = 32; o; o >>= 1) v += __shfl_xor(v, o, 64);
  return v;
}
__device__ __forceinline__ float wave_max(float v) {
#pragma unroll
  for (int o = 32; o; o >>= 1) v = fmaxf(v, __shfl_xor(v, o, 64));
  return v;
}

__global__ __launch_bounds__(256) void cast_bf16(const float* __restrict__ in,
                                                 unsigned short* __restrict__ out, long n) {
  long i = ((long)blockIdx.x * 256 + threadIdx.x) * 4;
  if (i >= n) return;
  float4 v = *(const float4*)&in[i];
  ushort4 o;
  o.x = f2bf(v.x); o.y = f2bf(v.y); o.z = f2bf(v.z); o.w = f2bf(v.w);
  *(ushort4*)&out[i] = o;
}

__global__ __launch_bounds__(256) void transpose_cast(const float* __restrict__ in,
                                                      unsigned short* __restrict__ out,
                                                      int R, int C) {
  __shared__ float tile[32][33];
  int c0 = blockIdx.x * 32, r0 = blockIdx.y * 32;
  int tx = threadIdx.x, ty = threadIdx.y;  // block (32,8)
  for (int i = ty; i < 32; i += 8) tile[i][tx] = in[(size_t)(r0 + i) * C + c0 + tx];
  __syncthreads();
  for (int i = ty; i < 32; i += 8) out[(size_t)(c0 + i) * R + r0 + tx] = f2bf(tile[tx][i]);
}

__global__ __launch_bounds__(256) void transpose_b16(const unsigned short* __restrict__ in,
                                                     unsigned short* __restrict__ out,
                                                     int R, int C) {
  __shared__ unsigned short tile[32][33];
  int c0 = blockIdx.x * 32, r0 = blockIdx.y * 32;
  size_t zb = (size_t)blockIdx.z * R * C;
  int tx = threadIdx.x, ty = threadIdx.y;  // block (32,8)
  for (int i = ty; i < 32; i += 8) tile[i][tx] = in[zb + (size_t)(r0 + i) * C + c0 + tx];
  __syncthreads();
  for (int i = ty; i < 32; i += 8) out[zb + (size_t)(c0 + i) * R + r0 + tx] = tile[tx][i];
}

__global__ __launch_bounds__(256) void softmax_rows(const unsigned short* __restrict__ g,
                                                    unsigned short* __restrict__ wout) {
  __shared__ float red[4];
  int row = blockIdx.x, t = threadIdx.x;
  const unsigned short* gr = g + ((size_t)row << 11) + t * 8;
  ushort4 ua = *(const ushort4*)gr;
  ushort4 ub = *(const ushort4*)(gr + 4);
  float a0 = h2f(ua.x), a1 = h2f(ua.y), a2 = h2f(ua.z), a3 = h2f(ua.w);
  float b0 = h2f(ub.x), b1 = h2f(ub.y), b2 = h2f(ub.z), b3 = h2f(ub.w);
  float mx = fmaxf(fmaxf(fmaxf(a0, a1), fmaxf(a2, a3)),
                   fmaxf(fmaxf(b0, b1), fmaxf(b2, b3)));
  mx = wave_max(mx);
  if ((t & 63) == 0) red[t >> 6] = mx;
  __syncthreads();
  mx = fmaxf(fmaxf(red[0], red[1]), fmaxf(red[2], red[3]));
  float e0 = __expf(a0 - mx), e1 = __expf(a1 - mx), e2 = __expf(a2 - mx), e3 = __expf(a3 - mx);
  float e4 = __expf(b0 - mx), e5 = __expf(b1 - mx), e6 = __expf(b2 - mx), e7 = __expf(b3 - mx);
  float s = ((e0 + e1) + (e2 + e3)) + ((e4 + e5) + (e6 + e7));
  s = wave_sum(s);
  __syncthreads();
  if ((t & 63) == 0) red[t >> 6] = s;
  __syncthreads();
  s = (red[0] + red[1]) + (red[2] + red[3]);
  float inv = 1.0f / s;
  ushort4 o0, o1;
  o0.x = f2bf(e0 * inv); o0.y = f2bf(e1 * inv); o0.z = f2bf(e2 * inv); o0.w = f2bf(e3 * inv);
  o1.x = f2bf(e4 * inv); o1.y = f2bf(e5 * inv); o1.z = f2bf(e6 * inv); o1.w = f2bf(e7 * inv);
  size_t base = ((size_t)row << 11) + t * 8;
  *(ushort4*)&wout[base] = o0;
  *(ushort4*)&wout[base + 4] = o1;
}

__global__ __launch_bounds__(256) void ln_residual_bf(const unsigned short* __restrict__ xb,
                                                      const float* __restrict__ attn,
                                                      unsigned short* __restrict__ outB) {
  __shared__ float red[4];
  int row = blockIdx.x, t = threadIdx.x;
  size_t base = ((size_t)row << 10) + t * 4;
  ushort4 ua = *(const ushort4*)&xb[base];
  float4 vb = *(const float4*)&attn[base];
  float4 v = {bf2f(ua.x) + vb.x, bf2f(ua.y) + vb.y, bf2f(ua.z) + vb.z, bf2f(ua.w) + vb.w};
  float s = (v.x + v.y) + (v.z + v.w);
  float ss = (v.x * v.x + v.y * v.y) + (v.z * v.z + v.w * v.w);
  s = wave_sum(s);
  if ((t & 63) == 0) red[t >> 6] = s;
  __syncthreads();
  s = (red[0] + red[1]) + (red[2] + red[3]);
  ss = wave_sum(ss);
  __syncthreads();
  if ((t & 63) == 0) red[t >> 6] = ss;
  __syncthreads();
  ss = (red[0] + red[1]) + (red[2] + red[3]);
  float mean = s * (1.0f / 1024.0f);
  float var = (ss - s * mean) * (1.0f / 1023.0f);
  float rstd = rsqrtf(var);
  ushort4 ob;
  ob.x = f2bf((v.x - mean) * rstd); ob.y = f2bf((v.y - mean) * rstd);
  ob.z = f2bf((v.z - mean) * rstd); ob.w = f2bf((v.w - mean) * rstd);
  *(ushort4*)&outB[base] = ob;
}

__global__ __launch_bounds__(256) void ln_residual_dot(const unsigned short* __restrict__ h2,
                                                       const unsigned short* __restrict__ post,
                                                       const float* __restrict__ readout,
                                                       float* __restrict__ rowdot) {
  __shared__ float red[4];
  int row = blockIdx.x, t = threadIdx.x;
  size_t base = ((size_t)row << 10) + t * 4;
  ushort4 ua = *(const ushort4*)&h2[base];
  ushort4 ub = *(const ushort4*)&post[base];
  float4 v = {bf2f(ua.x) + bf2f(ub.x), bf2f(ua.y) + bf2f(ub.y),
              bf2f(ua.z) + bf2f(ub.z), bf2f(ua.w) + bf2f(ub.w)};
  float s = (v.x + v.y) + (v.z + v.w);
  float ss = (v.x * v.x + v.y * v.y) + (v.z * v.z + v.w * v.w);
  s = wave_sum(s);
  if ((t & 63) == 0) red[t >> 6] = s;
  __syncthreads();
  s = (red[0] + red[1]) + (red[2] + red[3]);
  ss = wave_sum(ss);
  __syncthreads();
  if ((t & 63) == 0) red[t >> 6] = ss;
  __syncthreads();
  ss = (red[0] + red[1]) + (red[2] + red[3]);
  float mean = s * (1.0f / 1024.0f);
  float var = (ss - s * mean) * (1.0f / 1023.0f);
  float rstd = rsqrtf(var);
  float4 r = *(const float4*)&readout[t * 4];
  float dot = (v.x - mean) * rstd * r.x + (v.y - mean) * rstd * r.y +
              (v.z - mean) * rstd * r.z + (v.w - mean) * rstd * r.w;
  dot = wave_sum(dot);
  __syncthreads();
  if ((t & 63) == 0) red[t >> 6] = dot;
  __syncthreads();
  if (t == 0) rowdot[row] = (red[0] + red[1]) + (red[2] + red[3]);
}

__global__ __launch_bounds__(256) void reduce_out(const float* __restrict__ rowdot,
                                                  float* __restrict__ out) {
  __shared__ float red[4];
  int b = blockIdx.x, t = threadIdx.x;
  float s = 0.f;
  for (int i = t; i < 2048; i += 256) s += rowdot[(size_t)b * 2048 + i];
  s = wave_sum(s);
  if ((t & 63) == 0) red[t >> 6] = s;
  __syncthreads();
  if (t == 0) out[b] = ((red[0] + red[1]) + (red[2] + red[3])) * (1.0f / 65536.0f);
}

extern "C" void kernel_launch(void* const* d_in, const int* in_sizes, int n_in,
                              void* d_out, int out_size, void* d_ws, size_t ws_size,
                              hipStream_t stream) {
  const float* seq     = (const float*)d_in[0];  // [8,2048,768]
  const float* emb     = (const float*)d_in[1];  // [768,1024]
  const float* W1      = (const float*)d_in[2];  // [1024,1024]
  const float* W2      = (const float*)d_in[3];  // [1024,1024]
  const float* readout = (const float*)d_in[4];  // [1024]
  float* out = (float*)d_out;                    // [8]

  char* ws = (char*)d_ws;
  const size_t MB = 1024u * 1024u;
  // aliased layout (verified rounds 3-5):
  unsigned short* x_b    = (unsigned short*)(ws + 0);        // 32MB [G1..LN1]
  unsigned short* h2b    = (unsigned short*)(ws + 0);        // 32MB [FFN2..LN2]
  unsigned short* xT     = (unsigned short*)(ws + 32 * MB);  // 32MB [tr..attnV]
  unsigned short* hrelu  = (unsigned short*)(ws + 32 * MB);  // 32MB [FFN1..FFN2]
  unsigned short* gram   = (unsigned short*)(ws + 64 * MB);  // 64MB f16 [G2..sm]
  float*          attn   = (float*)(ws + 64 * MB);           // 64MB [aV..LN1]
  unsigned short* wts    = (unsigned short*)(ws + 128 * MB); // 64MB [sm..attnV]
  unsigned short* post_b = (unsigned short*)(ws + 128 * MB); // 32MB [LN1..LN2]
  unsigned short* seq_b  = (unsigned short*)(ws + 192 * MB); // 24MB [cast..G1]
  unsigned short* embT   = (unsigned short*)(ws + 216 * MB);
  unsigned short* W1T    = (unsigned short*)(ws + 218 * MB);
  unsigned short* W2T    = (unsigned short*)(ws + 220 * MB);
  float*          rowdot = (float*)(ws + 222 * MB);

  // 1. dtype prep
  cast_bf16<<<12288, 256, 0, stream>>>(seq, seq_b, 12582912L);
  transpose_cast<<<dim3(32, 24), dim3(32, 8), 0, stream>>>(emb, embT, 768, 1024);
  transpose_cast<<<dim3(32, 32), dim3(32, 8), 0, stream>>>(W1, W1T, 1024, 1024);
  transpose_cast<<<dim3(32, 32), dim3(32, 8), 0, stream>>>(W2, W2T, 1024, 1024);

  // 2. x = seq @ emb / sqrt(768)  -> bf16   (grid = 128*4 = 512)
  gemm_bt<<<512, 1024, 0, stream>>>(seq_b, embT, 16384, 1024, 768, 1, 0, 0, 0,
                                    0.03608439182435161f, EPI_BF, x_b);

  // 3. xT[b] = x[b]^T
  transpose_b16<<<dim3(32, 64, 8), dim3(32, 8), 0, stream>>>(x_b, xT, 2048, 1024);

  // 4. gram[b] = x[b] @ x[b]^T / 1024 -> f16  (grid = 8*16*8 = 1024)
  gemm_bt<<<1024, 1024, 0, stream>>>(x_b, x_b, 2048, 2048, 1024, 8,
                                     2048L * 1024, 2048L * 1024, 2048L * 2048,
                                     1.0f / 1024.0f, EPI_F16, gram);

  // 5. weights = softmax(gram) -> bf16
  softmax_rows<<<16384, 256, 0, stream>>>(gram, wts);

  // 6. attn[b] = weights[b] @ x[b] -> f32  (grid = 8*16*4 = 512)
  gemm_bt<<<512, 1024, 0, stream>>>(wts, xT, 2048, 1024, 2048, 8,
                                    2048L * 2048, 1024L * 2048, 2048L * 1024,
                                    1.0f, EPI_F32, attn);

  // 7. post = LN(x + attn) -> bf16
  ln_residual_bf<<<16384, 256, 0, stream>>>(x_b, attn, post_b);

  // 8. FFN (grids 128*4 = 512)
  gemm_bt<<<512, 1024, 0, stream>>>(post_b, W1T, 16384, 1024, 1024, 1, 0, 0, 0,
                                    0.03125f, EPI_RELUBF, hrelu);
  gemm_bt<<<512, 1024, 0, stream>>>(hrelu, W2T, 16384, 1024, 1024, 1, 0, 0, 0,
                                    0.03125f, EPI_BF, h2b);

  // 9. final LN + pooled readout
  ln_residual_dot<<<16384, 256, 0, stream>>>(h2b, post_b, readout, rowdot);
  reduce_out<<<8, 256, 0, stream>>>(rowdot, out);
}

// Round 7
// 385.161 us; speedup vs baseline: 1.0550x; 1.0550x over previous
//
#include <hip/hip_runtime.h>
#include <hip/hip_bf16.h>

typedef __bf16 bf16x8 __attribute__((ext_vector_type(8)));
typedef float f32x4 __attribute__((ext_vector_type(4)));

__device__ __forceinline__ unsigned short f2bf(float f) {
  union { float f; unsigned u; } x; x.f = f;
  unsigned r = x.u + 0x7fffu + ((x.u >> 16) & 1u);
  return (unsigned short)(r >> 16);
}
__device__ __forceinline__ float bf2f(unsigned short u) {
  union { unsigned u; float f; } x; x.u = (unsigned)u << 16;
  return x.f;
}
__device__ __forceinline__ unsigned short f2h(float f) {
  union { _Float16 h; unsigned short u; } x; x.h = (_Float16)f;
  return x.u;
}
__device__ __forceinline__ float h2f(unsigned short u) {
  union { _Float16 h; unsigned short u; } x; x.u = u;
  return (float)x.h;
}

__device__ __forceinline__ void async_ld16(const void* g, void* l) {
  __builtin_amdgcn_global_load_lds(
      (__attribute__((address_space(1))) void*)const_cast<void*>(g),
      (__attribute__((address_space(3))) void*)l, 16, 0, 0);
}

// ------------- 256x256 GEMM, 4-phase K-split pipelined schedule -------------
// BM=BN=256, BK=64, 512 thr (8 waves 2Mx4N), per-wave 128x64, acc[8][4].
// LDS 128KB: 2 dbuf x 4 parts {B-k0, A-k0, B-k1, A-k1}, part = [256 rows][32 k]
// bf16 (16KB, 2 gload_lds/thread). Per K-tile: 4 phases (kh x mf-half),
// 16 MFMA each, B-frags reused across mf-halves. One part of tile t+1 staged
// per phase. Gates: vmcnt(4)+s_barrier at kh-entries only (2 barriers/tile).
// Ledger (steady state, per-thread loads; part = 2 loads):
//   entry (t,kh0): outstanding = t:{B-k1,A-k1} + ... = 8 -> vmcnt(4) retires
//     t:{B-k0,A-k0}  (exactly what kh0's two phases read)
//   entry (t,kh1): outstanding = t:{B-k1,A-k1} + (t+1):{B-k0,A-k0} = 8 ->
//     vmcnt(4) retires t:{B-k1,A-k1}.  Last tile: vmcnt(0).
//   Loads land over ~4 phases -> HBM/L2 latency never exposed at the gate.
// WAR: stage of (t+1):part overwrites (t-1):part, last read >=1 barrier ago.
// Swizzle (both-sides): part slot-group = srcgrp ^ ((row>>1)&3); 2-way bank
// aliasing on ds_read_b128 (free per m136). Linear LDS dest, swizzled global
// source; read applies same XOR.

#define EPI_F32    0
#define EPI_BF     1
#define EPI_RELUBF 2
#define EPI_F16    3

__global__ __launch_bounds__(512, 2) void gemm_bt(
    const unsigned short* __restrict__ A,   // [nb][M][K] bf16
    const unsigned short* __restrict__ Bt,  // [nb][N][K] bf16
    int M, int N, int K, int nbatch,
    long sA, long sB, long sC,
    float scale, int mode, void* __restrict__ outp)
{
  __shared__ unsigned short lds[65536];  // 128 KB
  const int t = threadIdx.x;
  const int w = t >> 6, l = t & 63;
  const int lr = l & 15, lg = l >> 4;
  const int wr = w >> 2, wc = w & 3;           // 2 M-waves x 4 N-waves
  const int ntn = N >> 8;                      // N/256
  const int tiles = (M >> 8) * ntn;            // per batch
  const int chunk = (tiles * nbatch) >> 3;
  const int bid = blockIdx.x;
  const int wg = (bid & 7) * chunk + (bid >> 3);
  const int batch = wg / tiles;
  const int rem = wg - batch * tiles;
  const int row0 = (rem / ntn) << 8;
  const int col0 = (rem % ntn) << 8;

  const unsigned short* Ab  = A  + (long)batch * sA;
  const unsigned short* Btb = Bt + (long)batch * sB;

  // ds_read swizzle slot (elems): frag k-group lg at slot lg ^ ((row>>1)&3);
  // (row>>1)&3 == (lr>>1)&3 for all our frag rows (row = 16*m + lr).
  const int ks = ((lg ^ ((lr >> 1) & 3)) << 3);

  // staging geometry: lane covers row srow (+128 on round 1), k-group kg
  const int srow = w * 16 + (l >> 2);
  const int kgo  = (((l & 3) ^ ((l >> 3) & 3)) << 3);
  const long aoff0 = (long)(row0 + srow) * K + kgo;
  const long boff0 = (long)(col0 + srow) * K + kgo;
  const long off128 = (long)K << 7;

  const int NT = K >> 6;

  // stage one part (2 x gload_lds): partE = dest part base (elems)
#define STAGEP(partE, base, kcol)                                      \
  { async_ld16((base) + (kcol),          &lds[(partE) + t * 8]);       \
    async_ld16((base) + off128 + (kcol), &lds[(partE) + 4096 + t * 8]); }

  f32x4 acc[8][4];
#pragma unroll
  for (int m = 0; m < 8; ++m)
#pragma unroll
    for (int n = 0; n < 4; ++n) acc[m][n] = (f32x4){0.f, 0.f, 0.f, 0.f};

  // prologue: stage tile 0, all 4 parts, into buf0 (order: B-k0,A-k0,B-k1,A-k1)
  STAGEP(0,     Btb + boff0, 0);
  STAGEP(8192,  Ab + aoff0,  0);
  STAGEP(16384, Btb + boff0, 32);
  STAGEP(24576, Ab + aoff0,  32);
  __builtin_amdgcn_sched_barrier(0);

  for (int tt = 0; tt < NT; ++tt) {
    const int bufe  = (tt & 1) << 15;
    const int nbufe = ((tt + 1) & 1) << 15;
    const bool st = (tt + 1) < NT;
    const int kn = (tt + 1) << 6;

#pragma unroll
    for (int kh = 0; kh < 2; ++kh) {
      // ---- gate: this kh's parts (staged ~4 phases ago) must have landed
      if (kh == 0 || st) { asm volatile("s_waitcnt vmcnt(4)" ::: "memory"); }
      else               { asm volatile("s_waitcnt vmcnt(0)" ::: "memory"); }
      __builtin_amdgcn_sched_barrier(0);
      __builtin_amdgcn_s_barrier();
      __builtin_amdgcn_sched_barrier(0);

      const int pB = bufe + kh * 16384;
      const int pA = pB + 8192;

      bf16x8 bfr[4];
#pragma unroll
      for (int nf = 0; nf < 4; ++nf) {
        int rb = wc * 64 + nf * 16 + lr;
        bfr[nf] = *(const bf16x8*)&lds[pB + rb * 32 + ks];
      }
      // ---- phase (kh, mf-half 0)
      {
        bf16x8 af[4];
#pragma unroll
        for (int i = 0; i < 4; ++i) {
          int ra = wr * 128 + i * 16 + lr;
          af[i] = *(const bf16x8*)&lds[pA + ra * 32 + ks];
        }
        if (st) STAGEP(nbufe + kh * 16384, Btb + boff0, kn + kh * 32);
        __builtin_amdgcn_s_setprio(1);
#pragma unroll
        for (int i = 0; i < 4; ++i)
#pragma unroll
          for (int nf = 0; nf < 4; ++nf)
            acc[i][nf] = __builtin_amdgcn_mfma_f32_16x16x32_bf16(af[i], bfr[nf], acc[i][nf], 0, 0, 0);
        __builtin_amdgcn_s_setprio(0);
      }
      // ---- phase (kh, mf-half 1)
      {
        bf16x8 af[4];
#pragma unroll
        for (int i = 0; i < 4; ++i) {
          int ra = wr * 128 + 64 + i * 16 + lr;
          af[i] = *(const bf16x8*)&lds[pA + ra * 32 + ks];
        }
        if (st) STAGEP(nbufe + kh * 16384 + 8192, Ab + aoff0, kn + kh * 32);
        __builtin_amdgcn_s_setprio(1);
#pragma unroll
        for (int i = 0; i < 4; ++i)
#pragma unroll
          for (int nf = 0; nf < 4; ++nf)
            acc[4 + i][nf] = __builtin_amdgcn_mfma_f32_16x16x32_bf16(af[i], bfr[nf], acc[4 + i][nf], 0, 0, 0);
        __builtin_amdgcn_s_setprio(0);
      }
      __builtin_amdgcn_sched_barrier(0);
    }
  }

  float* outF = (float*)outp;
  unsigned short* outH = (unsigned short*)outp;
  const size_t cb = (size_t)batch * (size_t)sC;
#pragma unroll
  for (int mf = 0; mf < 8; ++mf) {
    int rbase = row0 + wr * 128 + mf * 16 + lg * 4;
#pragma unroll
    for (int nf = 0; nf < 4; ++nf) {
      int c = col0 + wc * 64 + nf * 16 + lr;
      f32x4 v = acc[mf][nf];
#pragma unroll
      for (int q = 0; q < 4; ++q) {
        size_t idx = cb + (size_t)(rbase + q) * N + c;
        float val = v[q] * scale;
        if (mode == EPI_F32)         outF[idx] = val;
        else if (mode == EPI_BF)     outH[idx] = f2bf(val);
        else if (mode == EPI_RELUBF) outH[idx] = f2bf(fmaxf(val, 0.f));
        else                         outH[idx] = f2h(val);
      }
    }
  }
#undef STAGEP
}

// ---------------- elementwise / reduction kernels (unchanged) ----------------

__device__ __forceinline__ float wave_sum(float v) {
#pragma unroll
  for (int o = 32; o; o >>= 1) v += __shfl_xor(v, o, 64);
  return v;
}
__device__ __forceinline__ float wave_max(float v) {
#pragma unroll
  for (int o = 32; o; o >>= 1) v = fmaxf(v, __shfl_xor(v, o, 64));
  return v;
}

__global__ __launch_bounds__(256) void cast_bf16(const float* __restrict__ in,
                                                 unsigned short* __restrict__ out, long n) {
  long i = ((long)blockIdx.x * 256 + threadIdx.x) * 4;
  if (i >= n) return;
  float4 v = *(const float4*)&in[i];
  ushort4 o;
  o.x = f2bf(v.x); o.y = f2bf(v.y); o.z = f2bf(v.z); o.w = f2bf(v.w);
  *(ushort4*)&out[i] = o;
}

__global__ __launch_bounds__(256) void transpose_cast(const float* __restrict__ in,
                                                      unsigned short* __restrict__ out,
                                                      int R, int C) {
  __shared__ float tile[32][33];
  int c0 = blockIdx.x * 32, r0 = blockIdx.y * 32;
  int tx = threadIdx.x, ty = threadIdx.y;  // block (32,8)
  for (int i = ty; i < 32; i += 8) tile[i][tx] = in[(size_t)(r0 + i) * C + c0 + tx];
  __syncthreads();
  for (int i = ty; i < 32; i += 8) out[(size_t)(c0 + i) * R + r0 + tx] = f2bf(tile[tx][i]);
}

__global__ __launch_bounds__(256) void transpose_b16(const unsigned short* __restrict__ in,
                                                     unsigned short* __restrict__ out,
                                                     int R, int C) {
  __shared__ unsigned short tile[32][33];
  int c0 = blockIdx.x * 32, r0 = blockIdx.y * 32;
  size_t zb = (size_t)blockIdx.z * R * C;
  int tx = threadIdx.x, ty = threadIdx.y;  // block (32,8)
  for (int i = ty; i < 32; i += 8) tile[i][tx] = in[zb + (size_t)(r0 + i) * C + c0 + tx];
  __syncthreads();
  for (int i = ty; i < 32; i += 8) out[zb + (size_t)(c0 + i) * R + r0 + tx] = tile[tx][i];
}

__global__ __launch_bounds__(256) void softmax_rows(const unsigned short* __restrict__ g,
                                                    unsigned short* __restrict__ wout) {
  __shared__ float red[4];
  int row = blockIdx.x, t = threadIdx.x;
  const unsigned short* gr = g + ((size_t)row << 11) + t * 8;
  ushort4 ua = *(const ushort4*)gr;
  ushort4 ub = *(const ushort4*)(gr + 4);
  float a0 = h2f(ua.x), a1 = h2f(ua.y), a2 = h2f(ua.z), a3 = h2f(ua.w);
  float b0 = h2f(ub.x), b1 = h2f(ub.y), b2 = h2f(ub.z), b3 = h2f(ub.w);
  float mx = fmaxf(fmaxf(fmaxf(a0, a1), fmaxf(a2, a3)),
                   fmaxf(fmaxf(b0, b1), fmaxf(b2, b3)));
  mx = wave_max(mx);
  if ((t & 63) == 0) red[t >> 6] = mx;
  __syncthreads();
  mx = fmaxf(fmaxf(red[0], red[1]), fmaxf(red[2], red[3]));
  float e0 = __expf(a0 - mx), e1 = __expf(a1 - mx), e2 = __expf(a2 - mx), e3 = __expf(a3 - mx);
  float e4 = __expf(b0 - mx), e5 = __expf(b1 - mx), e6 = __expf(b2 - mx), e7 = __expf(b3 - mx);
  float s = ((e0 + e1) + (e2 + e3)) + ((e4 + e5) + (e6 + e7));
  s = wave_sum(s);
  __syncthreads();
  if ((t & 63) == 0) red[t >> 6] = s;
  __syncthreads();
  s = (red[0] + red[1]) + (red[2] + red[3]);
  float inv = 1.0f / s;
  ushort4 o0, o1;
  o0.x = f2bf(e0 * inv); o0.y = f2bf(e1 * inv); o0.z = f2bf(e2 * inv); o0.w = f2bf(e3 * inv);
  o1.x = f2bf(e4 * inv); o1.y = f2bf(e5 * inv); o1.z = f2bf(e6 * inv); o1.w = f2bf(e7 * inv);
  size_t base = ((size_t)row << 11) + t * 8;
  *(ushort4*)&wout[base] = o0;
  *(ushort4*)&wout[base + 4] = o1;
}

__global__ __launch_bounds__(256) void ln_residual_bf(const unsigned short* __restrict__ xb,
                                                      const float* __restrict__ attn,
                                                      unsigned short* __restrict__ outB) {
  __shared__ float red[4];
  int row = blockIdx.x, t = threadIdx.x;
  size_t base = ((size_t)row << 10) + t * 4;
  ushort4 ua = *(const ushort4*)&xb[base];
  float4 vb = *(const float4*)&attn[base];
  float4 v = {bf2f(ua.x) + vb.x, bf2f(ua.y) + vb.y, bf2f(ua.z) + vb.z, bf2f(ua.w) + vb.w};
  float s = (v.x + v.y) + (v.z + v.w);
  float ss = (v.x * v.x + v.y * v.y) + (v.z * v.z + v.w * v.w);
  s = wave_sum(s);
  if ((t & 63) == 0) red[t >> 6] = s;
  __syncthreads();
  s = (red[0] + red[1]) + (red[2] + red[3]);
  ss = wave_sum(ss);
  __syncthreads();
  if ((t & 63) == 0) red[t >> 6] = ss;
  __syncthreads();
  ss = (red[0] + red[1]) + (red[2] + red[3]);
  float mean = s * (1.0f / 1024.0f);
  float var = (ss - s * mean) * (1.0f / 1023.0f);
  float rstd = rsqrtf(var);
  ushort4 ob;
  ob.x = f2bf((v.x - mean) * rstd); ob.y = f2bf((v.y - mean) * rstd);
  ob.z = f2bf((v.z - mean) * rstd); ob.w = f2bf((v.w - mean) * rstd);
  *(ushort4*)&outB[base] = ob;
}

__global__ __launch_bounds__(256) void ln_residual_dot(const unsigned short* __restrict__ h2,
                                                       const unsigned short* __restrict__ post,
                                                       const float* __restrict__ readout,
                                                       float* __restrict__ rowdot) {
  __shared__ float red[4];
  int row = blockIdx.x, t = threadIdx.x;
  size_t base = ((size_t)row << 10) + t * 4;
  ushort4 ua = *(const ushort4*)&h2[base];
  ushort4 ub = *(const ushort4*)&post[base];
  float4 v = {bf2f(ua.x) + bf2f(ub.x), bf2f(ua.y) + bf2f(ub.y),
              bf2f(ua.z) + bf2f(ub.z), bf2f(ua.w) + bf2f(ub.w)};
  float s = (v.x + v.y) + (v.z + v.w);
  float ss = (v.x * v.x + v.y * v.y) + (v.z * v.z + v.w * v.w);
  s = wave_sum(s);
  if ((t & 63) == 0) red[t >> 6] = s;
  __syncthreads();
  s = (red[0] + red[1]) + (red[2] + red[3]);
  ss = wave_sum(ss);
  __syncthreads();
  if ((t & 63) == 0) red[t >> 6] = ss;
  __syncthreads();
  ss = (red[0] + red[1]) + (red[2] + red[3]);
  float mean = s * (1.0f / 1024.0f);
  float var = (ss - s * mean) * (1.0f / 1023.0f);
  float rstd = rsqrtf(var);
  float4 r = *(const float4*)&readout[t * 4];
  float dot = (v.x - mean) * rstd * r.x + (v.y - mean) * rstd * r.y +
              (v.z - mean) * rstd * r.z + (v.w - mean) * rstd * r.w;
  dot = wave_sum(dot);
  __syncthreads();
  if ((t & 63) == 0) red[t >> 6] = dot;
  __syncthreads();
  if (t == 0) rowdot[row] = (red[0] + red[1]) + (red[2] + red[3]);
}

__global__ __launch_bounds__(256) void reduce_out(const float* __restrict__ rowdot,
                                                  float* __restrict__ out) {
  __shared__ float red[4];
  int b = blockIdx.x, t = threadIdx.x;
  float s = 0.f;
  for (int i = t; i < 2048; i += 256) s += rowdot[(size_t)b * 2048 + i];
  s = wave_sum(s);
  if ((t & 63) == 0) red[t >> 6] = s;
  __syncthreads();
  if (t == 0) out[b] = ((red[0] + red[1]) + (red[2] + red[3])) * (1.0f / 65536.0f);
}

extern "C" void kernel_launch(void* const* d_in, const int* in_sizes, int n_in,
                              void* d_out, int out_size, void* d_ws, size_t ws_size,
                              hipStream_t stream) {
  const float* seq     = (const float*)d_in[0];  // [8,2048,768]
  const float* emb     = (const float*)d_in[1];  // [768,1024]
  const float* W1      = (const float*)d_in[2];  // [1024,1024]
  const float* W2      = (const float*)d_in[3];  // [1024,1024]
  const float* readout = (const float*)d_in[4];  // [1024]
  float* out = (float*)d_out;                    // [8]

  char* ws = (char*)d_ws;
  const size_t MB = 1024u * 1024u;
  // aliased layout (verified rounds 3-6):
  unsigned short* x_b    = (unsigned short*)(ws + 0);        // 32MB [G1..LN1]
  unsigned short* h2b    = (unsigned short*)(ws + 0);        // 32MB [FFN2..LN2]
  unsigned short* xT     = (unsigned short*)(ws + 32 * MB);  // 32MB [tr..attnV]
  unsigned short* hrelu  = (unsigned short*)(ws + 32 * MB);  // 32MB [FFN1..FFN2]
  unsigned short* gram   = (unsigned short*)(ws + 64 * MB);  // 64MB f16 [G2..sm]
  float*          attn   = (float*)(ws + 64 * MB);           // 64MB [aV..LN1]
  unsigned short* wts    = (unsigned short*)(ws + 128 * MB); // 64MB [sm..attnV]
  unsigned short* post_b = (unsigned short*)(ws + 128 * MB); // 32MB [LN1..LN2]
  unsigned short* seq_b  = (unsigned short*)(ws + 192 * MB); // 24MB [cast..G1]
  unsigned short* embT   = (unsigned short*)(ws + 216 * MB);
  unsigned short* W1T    = (unsigned short*)(ws + 218 * MB);
  unsigned short* W2T    = (unsigned short*)(ws + 220 * MB);
  float*          rowdot = (float*)(ws + 222 * MB);

  // 1. dtype prep
  cast_bf16<<<12288, 256, 0, stream>>>(seq, seq_b, 12582912L);
  transpose_cast<<<dim3(32, 24), dim3(32, 8), 0, stream>>>(emb, embT, 768, 1024);
  transpose_cast<<<dim3(32, 32), dim3(32, 8), 0, stream>>>(W1, W1T, 1024, 1024);
  transpose_cast<<<dim3(32, 32), dim3(32, 8), 0, stream>>>(W2, W2T, 1024, 1024);

  // 2. x = seq @ emb / sqrt(768)  -> bf16   (grid = 64*4 = 256)
  gemm_bt<<<256, 512, 0, stream>>>(seq_b, embT, 16384, 1024, 768, 1, 0, 0, 0,
                                   0.03608439182435161f, EPI_BF, x_b);

  // 3. xT[b] = x[b]^T
  transpose_b16<<<dim3(32, 64, 8), dim3(32, 8), 0, stream>>>(x_b, xT, 2048, 1024);

  // 4. gram[b] = x[b] @ x[b]^T / 1024 -> f16  (grid = 8*8*8 = 512)
  gemm_bt<<<512, 512, 0, stream>>>(x_b, x_b, 2048, 2048, 1024, 8,
                                   2048L * 1024, 2048L * 1024, 2048L * 2048,
                                   1.0f / 1024.0f, EPI_F16, gram);

  // 5. weights = softmax(gram) -> bf16
  softmax_rows<<<16384, 256, 0, stream>>>(gram, wts);

  // 6. attn[b] = weights[b] @ x[b] -> f32  (grid = 8*4*8 = 256)
  gemm_bt<<<256, 512, 0, stream>>>(wts, xT, 2048, 1024, 2048, 8,
                                   2048L * 2048, 1024L * 2048, 2048L * 1024,
                                   1.0f, EPI_F32, attn);

  // 7. post = LN(x + attn) -> bf16
  ln_residual_bf<<<16384, 256, 0, stream>>>(x_b, attn, post_b);

  // 8. FFN (grids 64*4 = 256)
  gemm_bt<<<256, 512, 0, stream>>>(post_b, W1T, 16384, 1024, 1024, 1, 0, 0, 0,
                                   0.03125f, EPI_RELUBF, hrelu);
  gemm_bt<<<256, 512, 0, stream>>>(hrelu, W2T, 16384, 1024, 1024, 1, 0, 0, 0,
                                   0.03125f, EPI_BF, h2b);

  // 9. final LN + pooled readout
  ln_residual_dot<<<16384, 256, 0, stream>>>(h2b, post_b, readout, rowdot);
  reduce_out<<<8, 256, 0, stream>>>(rowdot, out);
}